// Round 4
// baseline (310.914 us; speedup 1.0000x reference)
//
#include <hip/hip_runtime.h>
#include <hip/hip_bf16.h>
#include <cstdint>

#define B_  4
#define LQ_ 2048
#define LK_ 2048
#define D_  1024
#define H_  16
#define HD_ 64

typedef __attribute__((ext_vector_type(8))) short bf16x8;   // 8 bf16 in 4 VGPRs
typedef __attribute__((ext_vector_type(4))) float f32x4;    // MFMA C/D

#if defined(__has_builtin)
#if __has_builtin(__builtin_amdgcn_exp2f)
#define EXP2F(x) __builtin_amdgcn_exp2f(x)
#else
#define EXP2F(x) exp2f(x)
#endif
#else
#define EXP2F(x) exp2f(x)
#endif

__device__ __forceinline__ unsigned short f2b(float f) {   // RNE
    union { float f; unsigned u; } v; v.f = f;
    unsigned u = v.u;
    unsigned r = (u + 0x7fffu + ((u >> 16) & 1u)) >> 16;
    return (unsigned short)r;
}

// async global->LDS, 16B per lane. LDS dest: wave-uniform base + lane*16.
__device__ __forceinline__ void gl_lds16(const unsigned short* g, unsigned short* l) {
    __builtin_amdgcn_global_load_lds(
        (const __attribute__((address_space(1))) unsigned int*)(g),
        (__attribute__((address_space(3))) unsigned int*)(l),
        16, 0, 0);
}

#define PHASE_BARRIER() do { \
    __builtin_amdgcn_sched_barrier(0); \
    __builtin_amdgcn_s_barrier(); \
    __builtin_amdgcn_sched_barrier(0); } while (0)

#define WAITVM(N) do { \
    asm volatile("s_waitcnt vmcnt(" #N ")" ::: "memory"); \
    __builtin_amdgcn_sched_barrier(0); } while (0)

// ---------------------------------------------------------------------------
// Fused fp32->bf16 for all 5 tensors; blockIdx.y selects. Wq scaled by s0.
// ---------------------------------------------------------------------------
__global__ void cvt_all(const float* __restrict__ a0, unsigned short* __restrict__ d0,
                        const float* __restrict__ a1, unsigned short* __restrict__ d1,
                        const float* __restrict__ w0, unsigned short* __restrict__ e0, float s0,
                        const float* __restrict__ w1, unsigned short* __restrict__ e1,
                        const float* __restrict__ w2, unsigned short* __restrict__ e2,
                        int nact, int nw) {
    const float* in; unsigned short* out; float s = 1.0f; int n;
    switch (blockIdx.y) {
        case 0: in = a0; out = d0; n = nact; break;
        case 1: in = a1; out = d1; n = nact; break;
        case 2: in = w0; out = e0; n = nw; s = s0; break;
        case 3: in = w1; out = e1; n = nw; break;
        default: in = w2; out = e2; n = nw; break;
    }
    int i = (blockIdx.x * blockDim.x + threadIdx.x) * 8;
    int stride = gridDim.x * blockDim.x * 8;
    for (; i < n; i += stride) {
        float4 x = *(const float4*)(in + i);
        float4 y = *(const float4*)(in + i + 4);
        bf16x8 v;
        v[0] = (short)f2b(x.x * s); v[1] = (short)f2b(x.y * s);
        v[2] = (short)f2b(x.z * s); v[3] = (short)f2b(x.w * s);
        v[4] = (short)f2b(y.x * s); v[5] = (short)f2b(y.y * s);
        v[6] = (short)f2b(y.z * s); v[7] = (short)f2b(y.w * s);
        *(bf16x8*)(out + i) = v;
    }
}

// ---------------------------------------------------------------------------
// Fused QKV projection GEMM v2 — 128x128 tile, BK=64, 4 waves (2M x 2N),
// same 4-phase counted-vmcnt schedule as round 1 (T3+T4+T5; 2 gl_lds per
// phase per thread -> identical vmcnt(6)/(4)/(0) ladder).
// Re-tiled for dispatch balance: grid = 64 m-tiles x 24 (proj x ntile)
// = 1536 blocks = 256 CUs x 6 exactly, LDS 64KB -> 2 blocks/CU co-resident.
// (Round-1 384-block/128KB config ran 1.5 rounds at 1 block/CU: 33% idle.)
// XCD swizzle: XCD <- m-octile, so each XCD re-reads only its 4MB X-slice
// (L2-resident); W (6MB) streams once per XCD.
// ---------------------------------------------------------------------------
__global__ __launch_bounds__(256, 2) void qkv_gemm(
    const unsigned short* __restrict__ Xq,
    const unsigned short* __restrict__ Xkv,
    const unsigned short* __restrict__ Wqb, const unsigned short* __restrict__ Wkb,
    const unsigned short* __restrict__ Wvb,
    const float* __restrict__ bq, const float* __restrict__ bk,
    const float* __restrict__ bv, float qscale,
    unsigned short* __restrict__ Qb, unsigned short* __restrict__ Kb,
    unsigned short* __restrict__ Vb)
{
    __shared__ unsigned short AS[4][4096];   // slot (2t+kh)&3 : 8 frags x 512
    __shared__ unsigned short BS[4][4096];

    // bid -> (mt, proj, nt0); XCD (bid&7) owns m-octile mt/8.
    const int bid  = blockIdx.x;
    const int xcd  = bid & 7;
    const int idx  = bid >> 3;          // 0..191
    const int mt   = xcd * 8 + (idx & 7);   // 0..63
    const int yy   = idx >> 3;          // 0..23
    const int proj = yy >> 3;
    const int nt0  = yy & 7;

    const unsigned short* X = (proj == 0) ? Xq : Xkv;
    const unsigned short* W = (proj == 0) ? Wqb : (proj == 1 ? Wkb : Wvb);
    const float* bias       = (proj == 0) ? bq  : (proj == 1 ? bk  : bv);
    unsigned short* Y       = (proj == 0) ? Qb  : (proj == 1 ? Kb  : Vb);
    const float bscale      = (proj == 0) ? qscale : 1.0f;

    const int tid  = threadIdx.x;
    const int lane = tid & 63;
    const int w    = tid >> 6;                 // 0..3
    const int wm   = w & 1, wn = w >> 1;       // 2M x 2N wave grid
    const int m0   = mt * 128;
    const int n0   = nt0 * 128;
    const int l15  = lane & 15, quad = lane >> 4;

    f32x4 acc[4][4] = {};

    // staging: wave w stages frags w and w+4 of each 8-frag half-slot
    const unsigned short* gA0 = X + (size_t)(m0 + w * 16 + l15) * 1024 + quad * 8;
    const unsigned short* gA1 = gA0 + 4 * 16 * 1024;
    const unsigned short* gB0 = W + (size_t)(n0 + w * 16 + l15) * 1024 + quad * 8;
    const unsigned short* gB1 = gB0 + 4 * 16 * 1024;

#define STAGE_A(slot, koff) do { \
    gl_lds16(gA0 + (koff), &AS[slot][w * 512 + lane * 8]); \
    gl_lds16(gA1 + (koff), &AS[slot][(w + 4) * 512 + lane * 8]); } while (0)
#define STAGE_B(slot, koff) do { \
    gl_lds16(gB0 + (koff), &BS[slot][w * 512 + lane * 8]); \
    gl_lds16(gB1 + (koff), &BS[slot][(w + 4) * 512 + lane * 8]); } while (0)

    const int aoff = (wm * 4) * 512 + lane * 8;   // my 4 m-frags
    const int boff = (wn * 4) * 512 + lane * 8;   // my 4 n-frags

    // prologue: tiles 0 (both halves) + tile 1 kh0, in ring-issue order
    STAGE_A(0, 0);   STAGE_B(0, 0);
    STAGE_A(1, 32);  STAGE_B(1, 32);
    STAGE_A(2, 64);  STAGE_B(2, 64);
    WAITVM(8);
    __builtin_amdgcn_s_barrier();
    __builtin_amdgcn_sched_barrier(0);

    #pragma unroll 2
    for (int t = 0; t < 16; ++t) {
        const int s0 = (2 * t) & 3;
        const int s1 = (2 * t + 1) & 3;
        const int s3 = (2 * t + 3) & 3;

        bf16x8 af[4], bf0, bf1;

        // ---- P1: kh0, n-frags 0,1 ----
        #pragma unroll
        for (int i = 0; i < 4; ++i)
            af[i] = *(const bf16x8*)(&AS[s0][aoff + i * 512]);
        bf0 = *(const bf16x8*)(&BS[s0][boff]);
        bf1 = *(const bf16x8*)(&BS[s0][boff + 512]);
        PHASE_BARRIER();
        __builtin_amdgcn_s_setprio(1);
        #pragma unroll
        for (int i = 0; i < 4; ++i) {
            acc[i][0] = __builtin_amdgcn_mfma_f32_16x16x32_bf16(af[i], bf0, acc[i][0], 0, 0, 0);
            acc[i][1] = __builtin_amdgcn_mfma_f32_16x16x32_bf16(af[i], bf1, acc[i][1], 0, 0, 0);
        }
        __builtin_amdgcn_s_setprio(0);
        if (t < 15) STAGE_A(s3, (t + 1) * 64 + 32);

        // ---- P2: kh0, n-frags 2,3 (af reused) ----
        bf0 = *(const bf16x8*)(&BS[s0][boff + 1024]);
        bf1 = *(const bf16x8*)(&BS[s0][boff + 1536]);
        if (t < 14) { WAITVM(6); } else { WAITVM(0); }
        PHASE_BARRIER();
        __builtin_amdgcn_s_setprio(1);
        #pragma unroll
        for (int i = 0; i < 4; ++i) {
            acc[i][2] = __builtin_amdgcn_mfma_f32_16x16x32_bf16(af[i], bf0, acc[i][2], 0, 0, 0);
            acc[i][3] = __builtin_amdgcn_mfma_f32_16x16x32_bf16(af[i], bf1, acc[i][3], 0, 0, 0);
        }
        __builtin_amdgcn_s_setprio(0);
        if (t < 15) STAGE_B(s3, (t + 1) * 64 + 32);

        // ---- P3: kh1, n-frags 0,1 ----
        #pragma unroll
        for (int i = 0; i < 4; ++i)
            af[i] = *(const bf16x8*)(&AS[s1][aoff + i * 512]);
        bf0 = *(const bf16x8*)(&BS[s1][boff]);
        bf1 = *(const bf16x8*)(&BS[s1][boff + 512]);
        PHASE_BARRIER();
        __builtin_amdgcn_s_setprio(1);
        #pragma unroll
        for (int i = 0; i < 4; ++i) {
            acc[i][0] = __builtin_amdgcn_mfma_f32_16x16x32_bf16(af[i], bf0, acc[i][0], 0, 0, 0);
            acc[i][1] = __builtin_amdgcn_mfma_f32_16x16x32_bf16(af[i], bf1, acc[i][1], 0, 0, 0);
        }
        __builtin_amdgcn_s_setprio(0);
        if (t < 14) STAGE_A(s0, (t + 2) * 64);

        // ---- P4: kh1, n-frags 2,3 ----
        bf0 = *(const bf16x8*)(&BS[s1][boff + 1024]);
        bf1 = *(const bf16x8*)(&BS[s1][boff + 1536]);
        if (t < 14) { WAITVM(6); } else if (t == 14) { WAITVM(4); }
        PHASE_BARRIER();
        __builtin_amdgcn_s_setprio(1);
        #pragma unroll
        for (int i = 0; i < 4; ++i) {
            acc[i][2] = __builtin_amdgcn_mfma_f32_16x16x32_bf16(af[i], bf0, acc[i][2], 0, 0, 0);
            acc[i][3] = __builtin_amdgcn_mfma_f32_16x16x32_bf16(af[i], bf1, acc[i][3], 0, 0, 0);
        }
        __builtin_amdgcn_s_setprio(0);
        if (t < 14) STAGE_B(s0, (t + 2) * 64);
    }

#undef STAGE_A
#undef STAGE_B

    float bvv[4];
    #pragma unroll
    for (int j = 0; j < 4; ++j)
        bvv[j] = bias[n0 + wn * 64 + j * 16 + l15] * bscale;

    #pragma unroll
    for (int i = 0; i < 4; ++i) {
        #pragma unroll
        for (int r = 0; r < 4; ++r) {
            int row = m0 + wm * 64 + i * 16 + quad * 4 + r;
            unsigned short* yp = Y + (size_t)row * 1024 + n0 + wn * 64;
            #pragma unroll
            for (int j = 0; j < 4; ++j)
                yp[j * 16 + l15] = f2b(acc[i][j][r] + bvv[j]);
        }
    }
}

// ---------------------------------------------------------------------------
// V transpose: Vb[b*2048+tok][h*64+d] -> Vt[((b*16+h)*64+d)][tok]
// ---------------------------------------------------------------------------
__global__ __launch_bounds__(256) void transpose_v(
    const unsigned short* __restrict__ Vb, unsigned short* __restrict__ Vt)
{
    __shared__ unsigned short L[64 * 72];
    const int t0 = blockIdx.x * 64, h = blockIdx.y, b = blockIdx.z;
    const int rr = threadIdx.x >> 3;
    const int cc = (threadIdx.x & 7) * 8;

    #pragma unroll
    for (int p = 0; p < 2; ++p) {
        int r = rr + p * 32;
        *(bf16x8*)(&L[r * 72 + cc]) =
            *(const bf16x8*)(Vb + (size_t)(b * 2048 + t0 + r) * 1024 + h * 64 + cc);
    }
    __syncthreads();
    #pragma unroll
    for (int p = 0; p < 2; ++p) {
        int d = rr + p * 32;
        bf16x8 v;
        #pragma unroll
        for (int j = 0; j < 8; ++j)
            v[j] = (short)L[(cc + j) * 72 + d];
        *(bf16x8*)(Vt + ((size_t)(b * 16 + h) * 64 + d) * 2048 + t0 + cc) = v;
    }
}

// ---------------------------------------------------------------------------
// Flash attention v8 (unchanged from round 3): shared LDS staging of K and V
// + XCD swizzle + K double-buffer with counted waits.
// LDS: K dbuf 32K + Vs 16K + Ps 32K = 80KB -> 2 blocks/CU.
// ---------------------------------------------------------------------------
__global__ __launch_bounds__(256, 2) void attn_kernel(
    const unsigned short* __restrict__ Q,
    const unsigned short* __restrict__ Kp,
    const unsigned short* __restrict__ Vt,
    float* __restrict__ Out)
{
    __shared__ unsigned short Ks[2][16 * 512]; // frag f=kt*2+dblk: K[kt*16+l15][dblk*32+quad*8+j]
    __shared__ unsigned short Vs[16 * 512];    // frag f=nt*4+hb:  V^T[nt*16+l15][hb*32+quad*8+j]
    __shared__ unsigned short Ps[4][4096];     // per-wave, per-half 1024: P[16q][64k] frag-ordered

    const int tid  = threadIdx.x;
    const int lane = tid & 63;
    const int w    = tid >> 6;
    const int l15  = lane & 15, quad = lane >> 4;

    // XCD swizzle: all 8 q-tiles of a (b,h) group share bid%8 -> same XCD,
    // K/V stay L2-resident (proven r2: FETCH 141MB -> 25MB).
    const int bid = blockIdx.x + (blockIdx.y << 3) + (blockIdx.z << 7);
    const int glo = bid & 7;
    const int jx  = bid >> 3;          // 0..63
    const int qt  = jx & 7;
    const int g   = glo + ((jx >> 3) << 3);   // 0..63: (b,h) group
    const int h   = g & 15;
    const int b   = g >> 4;

    bf16x8 qf[4][2];
    #pragma unroll
    for (int half = 0; half < 4; ++half) {
        const unsigned short* qptr =
            Q + (size_t)(b * LQ_ + qt * 256 + w * 64 + half * 16 + l15) * 1024 + h * 64;
        qf[half][0] = *(const bf16x8*)(qptr + quad * 8);
        qf[half][1] = *(const bf16x8*)(qptr + 32 + quad * 8);
    }

    bf16x8 ones;
    #pragma unroll
    for (int j = 0; j < 8; ++j) ones[j] = (short)0x3F80;   // bf16 1.0

    f32x4 oacc[4][4] = {};
    f32x4 lacc[4]    = {};

    const unsigned short* Kbase = Kp + (size_t)b * LK_ * 1024 + h * 64;
    const unsigned short* Vbase = Vt + (size_t)(b * 16 + h) * 64 * 2048;

    const unsigned short* gK[4];
    unsigned short* lK[4];                    // buffer-0 LDS dests
    const unsigned short* gV[4];
    unsigned short* lV[4];
    #pragma unroll
    for (int j = 0; j < 4; ++j) {
        int kt = w + (j >> 1) * 4, dblk = j & 1;
        gK[j] = Kbase + (size_t)(kt * 16 + l15) * 1024 + dblk * 32 + quad * 8;
        lK[j] = &Ks[0][(kt * 2 + dblk) * 512 + lane * 8];
        gV[j] = Vbase + (size_t)(w * 16 + l15) * 2048 + j * 32 + quad * 8;
        lV[j] = &Vs[(w * 4 + j) * 512 + lane * 8];
    }

    // P region: element (q,k) at half*1024 + (k>>3)*128 + q*8 + (k&7)
    const int pws = (quad >> 1) * 128 + l15 * 8 + (quad & 1) * 4;
    unsigned short* PwB = &Ps[w][pws];            // + half*1024 + ti*256
    const unsigned short* PrB = &Ps[w][lane * 8]; // + half*1024 + hbl*512
    const unsigned short* KfrB = &Ks[0][lane * 8];
    const unsigned short* Vfr = &Vs[lane * 8];

    // prologue: stage K(0) into buffer 0
    #pragma unroll
    for (int j = 0; j < 4; ++j) gl_lds16(gK[j], lK[j]);

    for (int t = 0; t < 16; ++t) {
        const int cur = t & 1;
        const int k0 = t * 128;

        // stage V(t); prefetch K(t+1) into other buffer
        #pragma unroll
        for (int j = 0; j < 4; ++j) gl_lds16(gV[j] + k0, lV[j]);
        if (t < 15) {
            const int stoff = (cur ^ 1) * 8192;
            #pragma unroll
            for (int j = 0; j < 4; ++j)
                gl_lds16(gK[j] + (size_t)(t + 1) * (128 * 1024), lK[j] + stoff);
        }
        if (t == 0) {          // K(0) landed (V(0)+K(1) = 8 still in flight)
            WAITVM(8);
            PHASE_BARRIER();
        }
        const unsigned short* Kfr = KfrB + cur * 8192;

        #pragma unroll
        for (int cc = 0; cc < 2; ++cc) {          // two 64-key chunks
            // ---- QK^T, all 4 halves share each kf read ----
            f32x4 st[4][4] = {};
            #pragma unroll
            for (int ti = 0; ti < 4; ++ti)
                #pragma unroll
                for (int dblk = 0; dblk < 2; ++dblk) {
                    bf16x8 kf = *(const bf16x8*)(Kfr + ((cc * 4 + ti) * 2 + dblk) * 512);
                    #pragma unroll
                    for (int half = 0; half < 4; ++half)
                        st[half][ti] = __builtin_amdgcn_mfma_f32_16x16x32_bf16(
                            kf, qf[half][dblk], st[half][ti], 0, 0, 0);
                }

            // ---- p = exp2(s); pack (RHU) into per-half P regions ----
            #pragma unroll
            for (int half = 0; half < 4; ++half) {
                unsigned short* pw = PwB + half * 1024;
                #pragma unroll
                for (int ti = 0; ti < 4; ++ti) {
                    unsigned u0 = __float_as_uint(EXP2F(st[half][ti][0])) + 0x8000u;
                    unsigned u1 = __float_as_uint(EXP2F(st[half][ti][1])) + 0x8000u;
                    unsigned u2 = __float_as_uint(EXP2F(st[half][ti][2])) + 0x8000u;
                    unsigned u3 = __float_as_uint(EXP2F(st[half][ti][3])) + 0x8000u;
                    uint2 pk;
                    pk.x = __builtin_amdgcn_perm(u1, u0, 0x07060302);
                    pk.y = __builtin_amdgcn_perm(u3, u2, 0x07060302);
                    *(uint2*)(pw + ti * 256) = pk;
                }
            }

            // ---- after chunk0's compute has covered V latency: V ready ----
            if (cc == 0) {
                if (t < 15) { WAITVM(4); } else { WAITVM(0); }
                PHASE_BARRIER();      // Vs visible to all waves
            }

            // ---- PV + ones row-sum; vf read once per (nt,hbl), shared ----
            #pragma unroll
            for (int hbl = 0; hbl < 2; ++hbl) {
                bf16x8 pf[4];
                #pragma unroll
                for (int half = 0; half < 4; ++half) {
                    pf[half] = *(const bf16x8*)(PrB + half * 1024 + hbl * 512);
                    lacc[half] = __builtin_amdgcn_mfma_f32_16x16x32_bf16(
                        pf[half], ones, lacc[half], 0, 0, 0);
                }
                int hb = cc * 2 + hbl;
                #pragma unroll
                for (int nt = 0; nt < 4; ++nt) {
                    bf16x8 vf = *(const bf16x8*)(Vfr + (nt * 4 + hb) * 512);
                    #pragma unroll
                    for (int half = 0; half < 4; ++half)
                        oacc[half][nt] = __builtin_amdgcn_mfma_f32_16x16x32_bf16(
                            pf[half], vf, oacc[half][nt], 0, 0, 0);
                }
            }
        }

        if (t < 15) {
            WAITVM(0);        // K(t+1): issued a full tile of MFMA ago — free
            PHASE_BARRIER();  // K visible; Vs safe to overwrite next tile
        }
    }

    // ---- normalize + store ----
    #pragma unroll
    for (int half = 0; half < 4; ++half) {
        float il[4];
        #pragma unroll
        for (int r = 0; r < 4; ++r) il[r] = 1.0f / lacc[half][r];
        #pragma unroll
        for (int nt = 0; nt < 4; ++nt) {
            #pragma unroll
            for (int r = 0; r < 4; ++r) {
                size_t orow = (size_t)(b * LQ_ + qt * 256 + w * 64 + half * 16 + quad * 4 + r);
                Out[orow * 1024 + h * 64 + nt * 16 + l15] = oacc[half][nt][r] * il[r];
            }
        }
    }
}

// ---------------------------------------------------------------------------
extern "C" void kernel_launch(void* const* d_in, const int* in_sizes, int n_in,
                              void* d_out, int out_size, void* d_ws, size_t ws_size,
                              hipStream_t stream) {
    const float* zt = (const float*)d_in[0];
    const float* ic = (const float*)d_in[1];
    const float* Wq = (const float*)d_in[2];
    const float* bq = (const float*)d_in[3];
    const float* Wk = (const float*)d_in[4];
    const float* bk = (const float*)d_in[5];
    const float* Wv = (const float*)d_in[6];
    const float* bv = (const float*)d_in[7];
    float* out = (float*)d_out;

    const size_t M8 = (size_t)8192 * 1024;
    const size_t M1 = (size_t)1024 * 1024;
    unsigned short* Qb  = (unsigned short*)d_ws;
    unsigned short* Kb  = Qb  + M8;
    unsigned short* Vb  = Kb  + M8;
    unsigned short* Xz  = Vb  + M8;
    unsigned short* Xi  = Xz  + M8;
    unsigned short* Wqb = Xi  + M8;
    unsigned short* Wkb = Wqb + M1;
    unsigned short* Wvb = Wkb + M1;
    unsigned short* Vtb = Xz;                // Xz dead after qkv_gemm

    const float qscale = 0.125f * 1.44269504088896f;  // 1/sqrt(64) * log2(e)

    dim3 gcv(4096, 5);
    cvt_all<<<gcv, 256, 0, stream>>>(zt, Xz, ic, Xi,
                                     Wq, Wqb, qscale, Wk, Wkb, Wv, Wvb,
                                     (int)M8, (int)M1);

    qkv_gemm<<<dim3(1536), 256, 0, stream>>>(Xz, Xi, Wqb, Wkb, Wvb,
                                             bq, bk, bv, qscale, Qb, Kb, Vb);

    dim3 gtr(32, 16, 4);
    transpose_v<<<gtr, 256, 0, stream>>>(Vb, Vtb);

    dim3 gattn(8, 16, 4);                    // flattened+swizzled inside kernel
    attn_kernel<<<gattn, 256, 0, stream>>>(Qb, Kb, Vtb, out);
}

// Round 5
// 307.864 us; speedup vs baseline: 1.0099x; 1.0099x over previous
//
#include <hip/hip_runtime.h>
#include <hip/hip_bf16.h>
#include <cstdint>

#define B_  4
#define LQ_ 2048
#define LK_ 2048
#define D_  1024
#define H_  16
#define HD_ 64

typedef __attribute__((ext_vector_type(8))) short bf16x8;   // 8 bf16 in 4 VGPRs
typedef __attribute__((ext_vector_type(4))) short bf16x4;   // 4 bf16 in 2 VGPRs
typedef __attribute__((ext_vector_type(4))) float f32x4;    // MFMA C/D

#if defined(__has_builtin)
#if __has_builtin(__builtin_amdgcn_exp2f)
#define EXP2F(x) __builtin_amdgcn_exp2f(x)
#else
#define EXP2F(x) exp2f(x)
#endif
#else
#define EXP2F(x) exp2f(x)
#endif

__device__ __forceinline__ unsigned short f2b(float f) {   // RNE
    union { float f; unsigned u; } v; v.f = f;
    unsigned u = v.u;
    unsigned r = (u + 0x7fffu + ((u >> 16) & 1u)) >> 16;
    return (unsigned short)r;
}

// async global->LDS, 16B per lane. LDS dest: wave-uniform base + lane*16.
__device__ __forceinline__ void gl_lds16(const unsigned short* g, unsigned short* l) {
    __builtin_amdgcn_global_load_lds(
        (const __attribute__((address_space(1))) unsigned int*)(g),
        (__attribute__((address_space(3))) unsigned int*)(l),
        16, 0, 0);
}

#define PHASE_BARRIER() do { \
    __builtin_amdgcn_sched_barrier(0); \
    __builtin_amdgcn_s_barrier(); \
    __builtin_amdgcn_sched_barrier(0); } while (0)

#define WAITVM(N) do { \
    asm volatile("s_waitcnt vmcnt(" #N ")" ::: "memory"); \
    __builtin_amdgcn_sched_barrier(0); } while (0)

// ---------------------------------------------------------------------------
// Fused fp32->bf16 for all 5 tensors; blockIdx.y selects. Wq scaled by s0.
// ---------------------------------------------------------------------------
__global__ void cvt_all(const float* __restrict__ a0, unsigned short* __restrict__ d0,
                        const float* __restrict__ a1, unsigned short* __restrict__ d1,
                        const float* __restrict__ w0, unsigned short* __restrict__ e0, float s0,
                        const float* __restrict__ w1, unsigned short* __restrict__ e1,
                        const float* __restrict__ w2, unsigned short* __restrict__ e2,
                        int nact, int nw) {
    const float* in; unsigned short* out; float s = 1.0f; int n;
    switch (blockIdx.y) {
        case 0: in = a0; out = d0; n = nact; break;
        case 1: in = a1; out = d1; n = nact; break;
        case 2: in = w0; out = e0; n = nw; s = s0; break;
        case 3: in = w1; out = e1; n = nw; break;
        default: in = w2; out = e2; n = nw; break;
    }
    int i = (blockIdx.x * blockDim.x + threadIdx.x) * 8;
    int stride = gridDim.x * blockDim.x * 8;
    for (; i < n; i += stride) {
        float4 x = *(const float4*)(in + i);
        float4 y = *(const float4*)(in + i + 4);
        bf16x8 v;
        v[0] = (short)f2b(x.x * s); v[1] = (short)f2b(x.y * s);
        v[2] = (short)f2b(x.z * s); v[3] = (short)f2b(x.w * s);
        v[4] = (short)f2b(y.x * s); v[5] = (short)f2b(y.y * s);
        v[6] = (short)f2b(y.z * s); v[7] = (short)f2b(y.w * s);
        *(bf16x8*)(out + i) = v;
    }
}

// ---------------------------------------------------------------------------
// Fused QKV projection GEMM — round-1 version (measured best ~91us).
// 256x256 tile, BK=64, 8 waves (2M x 4N), 4-phase counted-vmcnt schedule
// (T3+T4+T5), 4-slot half-tile LDS ring (128KB), fragment-ordered.
// Round-4 lesson: 128^2 re-tile with perfectly balanced grid was SLOWER
// (106us, MfmaUtil 19%) — per-phase MFMA density beats dispatch balance.
// ---------------------------------------------------------------------------
__global__ __launch_bounds__(512, 2) void qkv_gemm(
    const unsigned short* __restrict__ Xq,
    const unsigned short* __restrict__ Xkv,
    const unsigned short* __restrict__ Wqb, const unsigned short* __restrict__ Wkb,
    const unsigned short* __restrict__ Wvb,
    const float* __restrict__ bq, const float* __restrict__ bk,
    const float* __restrict__ bv, float qscale,
    unsigned short* __restrict__ Qb, unsigned short* __restrict__ Kb,
    unsigned short* __restrict__ Vb)
{
    __shared__ unsigned short AS[4][8192];   // slot (2t+kh)&3 : 16 frags x 512
    __shared__ unsigned short BS[4][8192];

    const int proj = blockIdx.y >> 2;
    const int nt0  = blockIdx.y & 3;
    const unsigned short* X = (proj == 0) ? Xq : Xkv;
    const unsigned short* W = (proj == 0) ? Wqb : (proj == 1 ? Wkb : Wvb);
    const float* bias       = (proj == 0) ? bq  : (proj == 1 ? bk  : bv);
    unsigned short* Y       = (proj == 0) ? Qb  : (proj == 1 ? Kb  : Vb);
    const float bscale      = (proj == 0) ? qscale : 1.0f;

    const int tid  = threadIdx.x;
    const int lane = tid & 63;
    const int w    = tid >> 6;                 // 0..7
    const int wm   = w & 1, wn = w >> 1;       // 2M x 4N wave grid
    const int m0   = blockIdx.x * 256;
    const int n0   = nt0 * 256;
    const int l15  = lane & 15, quad = lane >> 4;

    f32x4 acc[8][4] = {};

    // staging sources: wave w stages frags w*2, w*2+1 of each 16-frag half
    const unsigned short* gA0 = X + (size_t)(m0 + (w * 2) * 16 + l15) * 1024 + quad * 8;
    const unsigned short* gA1 = gA0 + 16 * 1024;
    const unsigned short* gB0 = W + (size_t)(n0 + (w * 2) * 16 + l15) * 1024 + quad * 8;
    const unsigned short* gB1 = gB0 + 16 * 1024;

#define STAGE_A(slot, koff) do { \
    gl_lds16(gA0 + (koff), &AS[slot][(w * 2) * 512 + lane * 8]); \
    gl_lds16(gA1 + (koff), &AS[slot][(w * 2 + 1) * 512 + lane * 8]); } while (0)
#define STAGE_B(slot, koff) do { \
    gl_lds16(gB0 + (koff), &BS[slot][(w * 2) * 512 + lane * 8]); \
    gl_lds16(gB1 + (koff), &BS[slot][(w * 2 + 1) * 512 + lane * 8]); } while (0)

    const int aoff = (wm * 8) * 512 + lane * 8;   // my 8 m-frags
    const int boff = (wn * 4) * 512 + lane * 8;   // my 4 n-frags

    // prologue: tiles 0 (both halves) + tile 1 kh0, in ring-issue order
    STAGE_A(0, 0);   STAGE_B(0, 0);
    STAGE_A(1, 32);  STAGE_B(1, 32);
    STAGE_A(2, 64);  STAGE_B(2, 64);
    WAITVM(8);
    __builtin_amdgcn_s_barrier();
    __builtin_amdgcn_sched_barrier(0);

    #pragma unroll 2
    for (int t = 0; t < 16; ++t) {
        const int s0 = (2 * t) & 3;
        const int s1 = (2 * t + 1) & 3;
        const int s3 = (2 * t + 3) & 3;

        bf16x8 af[8], bf0, bf1;

        // ---- P1: kh0, n-frags 0,1 ----
        #pragma unroll
        for (int i = 0; i < 8; ++i)
            af[i] = *(const bf16x8*)(&AS[s0][aoff + i * 512]);
        bf0 = *(const bf16x8*)(&BS[s0][boff]);
        bf1 = *(const bf16x8*)(&BS[s0][boff + 512]);
        PHASE_BARRIER();
        __builtin_amdgcn_s_setprio(1);
        #pragma unroll
        for (int i = 0; i < 8; ++i) {
            acc[i][0] = __builtin_amdgcn_mfma_f32_16x16x32_bf16(af[i], bf0, acc[i][0], 0, 0, 0);
            acc[i][1] = __builtin_amdgcn_mfma_f32_16x16x32_bf16(af[i], bf1, acc[i][1], 0, 0, 0);
        }
        __builtin_amdgcn_s_setprio(0);
        if (t < 15) STAGE_A(s3, (t + 1) * 64 + 32);

        // ---- P2: kh0, n-frags 2,3 (af reused) ----
        bf0 = *(const bf16x8*)(&BS[s0][boff + 1024]);
        bf1 = *(const bf16x8*)(&BS[s0][boff + 1536]);
        if (t < 14) { WAITVM(6); } else { WAITVM(0); }
        PHASE_BARRIER();
        __builtin_amdgcn_s_setprio(1);
        #pragma unroll
        for (int i = 0; i < 8; ++i) {
            acc[i][2] = __builtin_amdgcn_mfma_f32_16x16x32_bf16(af[i], bf0, acc[i][2], 0, 0, 0);
            acc[i][3] = __builtin_amdgcn_mfma_f32_16x16x32_bf16(af[i], bf1, acc[i][3], 0, 0, 0);
        }
        __builtin_amdgcn_s_setprio(0);
        if (t < 15) STAGE_B(s3, (t + 1) * 64 + 32);

        // ---- P3: kh1, n-frags 0,1 ----
        #pragma unroll
        for (int i = 0; i < 8; ++i)
            af[i] = *(const bf16x8*)(&AS[s1][aoff + i * 512]);
        bf0 = *(const bf16x8*)(&BS[s1][boff]);
        bf1 = *(const bf16x8*)(&BS[s1][boff + 512]);
        PHASE_BARRIER();
        __builtin_amdgcn_s_setprio(1);
        #pragma unroll
        for (int i = 0; i < 8; ++i) {
            acc[i][0] = __builtin_amdgcn_mfma_f32_16x16x32_bf16(af[i], bf0, acc[i][0], 0, 0, 0);
            acc[i][1] = __builtin_amdgcn_mfma_f32_16x16x32_bf16(af[i], bf1, acc[i][1], 0, 0, 0);
        }
        __builtin_amdgcn_s_setprio(0);
        if (t < 14) STAGE_A(s0, (t + 2) * 64);

        // ---- P4: kh1, n-frags 2,3 ----
        bf0 = *(const bf16x8*)(&BS[s1][boff + 1024]);
        bf1 = *(const bf16x8*)(&BS[s1][boff + 1536]);
        if (t < 14) { WAITVM(6); } else if (t == 14) { WAITVM(4); }
        PHASE_BARRIER();
        __builtin_amdgcn_s_setprio(1);
        #pragma unroll
        for (int i = 0; i < 8; ++i) {
            acc[i][2] = __builtin_amdgcn_mfma_f32_16x16x32_bf16(af[i], bf0, acc[i][2], 0, 0, 0);
            acc[i][3] = __builtin_amdgcn_mfma_f32_16x16x32_bf16(af[i], bf1, acc[i][3], 0, 0, 0);
        }
        __builtin_amdgcn_s_setprio(0);
        if (t < 14) STAGE_B(s0, (t + 2) * 64);
    }

#undef STAGE_A
#undef STAGE_B

    float bvv[4];
    #pragma unroll
    for (int j = 0; j < 4; ++j)
        bvv[j] = bias[n0 + wn * 64 + j * 16 + l15] * bscale;

    #pragma unroll
    for (int i = 0; i < 8; ++i) {
        #pragma unroll
        for (int r = 0; r < 4; ++r) {
            int row = m0 + wm * 128 + i * 16 + quad * 4 + r;
            unsigned short* yp = Y + (size_t)row * 1024 + n0 + wn * 64;
            #pragma unroll
            for (int j = 0; j < 4; ++j)
                yp[j * 16 + l15] = f2b(acc[i][j][r] + bvv[j]);
        }
    }
}

// ---------------------------------------------------------------------------
// V transpose: Vb[b*2048+tok][h*64+d] -> Vt[((b*16+h)*64+d)][tok]
// ---------------------------------------------------------------------------
__global__ __launch_bounds__(256) void transpose_v(
    const unsigned short* __restrict__ Vb, unsigned short* __restrict__ Vt)
{
    __shared__ unsigned short L[64 * 72];
    const int t0 = blockIdx.x * 64, h = blockIdx.y, b = blockIdx.z;
    const int rr = threadIdx.x >> 3;
    const int cc = (threadIdx.x & 7) * 8;

    #pragma unroll
    for (int p = 0; p < 2; ++p) {
        int r = rr + p * 32;
        *(bf16x8*)(&L[r * 72 + cc]) =
            *(const bf16x8*)(Vb + (size_t)(b * 2048 + t0 + r) * 1024 + h * 64 + cc);
    }
    __syncthreads();
    #pragma unroll
    for (int p = 0; p < 2; ++p) {
        int d = rr + p * 32;
        bf16x8 v;
        #pragma unroll
        for (int j = 0; j < 8; ++j)
            v[j] = (short)L[(cc + j) * 72 + d];
        *(bf16x8*)(Vt + ((size_t)(b * 16 + h) * 64 + d) * 2048 + t0 + cc) = v;
    }
}

// ---------------------------------------------------------------------------
// Flash attention v9: Ps LDS round-trip ELIMINATED.
// Swapped QK^T (mfma(K,Q)) leaves st[half][ti][r] = P[q=l15][key=ti*16+quad*4+r]
// — which is EXACTLY the A-fragment of mfma_f32_16x16x16bf16_1k (K=16:
// A[row=l&15][k=quad*4+j]). So PV switches to K=16 MFMA and P never leaves
// registers: exp2+pack produce pf[half][ti] (bf16x4) in-lane, zero cross-lane
// movement. Removes per chunk/wave: 16 ds_write_b64 + 8 ds_read_b128 + 2
// serial lgkm waits + Ps bank conflicts; LDS 80KB -> 48KB.
// V fragments for K=16 read from the UNCHANGED Vs layout at computed
// addresses: key s*16+quad*4+j lives at frag nt*4+(s>>1),
// lane' = ((s&1)*2+(quad>>1))*16+l15, elem (quad&1)*4 -> ds_read_b64.
// Rest (XCD swizzle, K dbuf, counted waits) as v8.
// ---------------------------------------------------------------------------
__global__ __launch_bounds__(256, 2) void attn_kernel(
    const unsigned short* __restrict__ Q,
    const unsigned short* __restrict__ Kp,
    const unsigned short* __restrict__ Vt,
    float* __restrict__ Out)
{
    __shared__ unsigned short Ks[2][16 * 512]; // frag f=kt*2+dblk: K[kt*16+l15][dblk*32+quad*8+j]
    __shared__ unsigned short Vs[16 * 512];    // frag f=nt*4+hb:  V^T[nt*16+l15][hb*32+quad*8+j]

    const int tid  = threadIdx.x;
    const int lane = tid & 63;
    const int w    = tid >> 6;
    const int l15  = lane & 15, quad = lane >> 4;

    // XCD swizzle: all 8 q-tiles of a (b,h) group share bid%8 -> same XCD,
    // K/V stay L2-resident (proven r2: FETCH 141MB -> 25MB).
    const int bid = blockIdx.x + (blockIdx.y << 3) + (blockIdx.z << 7);
    const int glo = bid & 7;
    const int jx  = bid >> 3;          // 0..63
    const int qt  = jx & 7;
    const int g   = glo + ((jx >> 3) << 3);   // 0..63: (b,h) group
    const int h   = g & 15;
    const int b   = g >> 4;

    bf16x8 qf[4][2];
    #pragma unroll
    for (int half = 0; half < 4; ++half) {
        const unsigned short* qptr =
            Q + (size_t)(b * LQ_ + qt * 256 + w * 64 + half * 16 + l15) * 1024 + h * 64;
        qf[half][0] = *(const bf16x8*)(qptr + quad * 8);
        qf[half][1] = *(const bf16x8*)(qptr + 32 + quad * 8);
    }

    bf16x4 ones4;
    #pragma unroll
    for (int j = 0; j < 4; ++j) ones4[j] = (short)0x3F80;   // bf16 1.0

    f32x4 oacc[4][4] = {};
    f32x4 lacc[4]    = {};

    const unsigned short* Kbase = Kp + (size_t)b * LK_ * 1024 + h * 64;
    const unsigned short* Vbase = Vt + (size_t)(b * 16 + h) * 64 * 2048;

    const unsigned short* gK[4];
    unsigned short* lK[4];                    // buffer-0 LDS dests
    const unsigned short* gV[4];
    unsigned short* lV[4];
    #pragma unroll
    for (int j = 0; j < 4; ++j) {
        int kt = w + (j >> 1) * 4, dblk = j & 1;
        gK[j] = Kbase + (size_t)(kt * 16 + l15) * 1024 + dblk * 32 + quad * 8;
        lK[j] = &Ks[0][(kt * 2 + dblk) * 512 + lane * 8];
        gV[j] = Vbase + (size_t)(w * 16 + l15) * 2048 + j * 32 + quad * 8;
        lV[j] = &Vs[(w * 4 + j) * 512 + lane * 8];
    }

    const unsigned short* KfrB = &Ks[0][lane * 8];
    // V K=16 fragment read base (see header comment): per-lane part
    const unsigned short* VfrB = &Vs[(quad >> 1) * 128 + l15 * 8 + (quad & 1) * 4];
    // + (nt*4 + (s>>1))*512 + (s&1)*256

    // prologue: stage K(0) into buffer 0
    #pragma unroll
    for (int j = 0; j < 4; ++j) gl_lds16(gK[j], lK[j]);

    for (int t = 0; t < 16; ++t) {
        const int cur = t & 1;
        const int k0 = t * 128;

        // stage V(t); prefetch K(t+1) into other buffer
        #pragma unroll
        for (int j = 0; j < 4; ++j) gl_lds16(gV[j] + k0, lV[j]);
        if (t < 15) {
            const int stoff = (cur ^ 1) * 8192;
            #pragma unroll
            for (int j = 0; j < 4; ++j)
                gl_lds16(gK[j] + (size_t)(t + 1) * (128 * 1024), lK[j] + stoff);
        }
        if (t == 0) {          // K(0) landed (V(0)+K(1) = 8 still in flight)
            WAITVM(8);
            PHASE_BARRIER();
        }
        const unsigned short* Kfr = KfrB + cur * 8192;

        #pragma unroll
        for (int cc = 0; cc < 2; ++cc) {          // two 64-key chunks
            // ---- QK^T, all 4 halves share each kf read ----
            f32x4 st[4][4] = {};
            #pragma unroll
            for (int ti = 0; ti < 4; ++ti)
                #pragma unroll
                for (int dblk = 0; dblk < 2; ++dblk) {
                    bf16x8 kf = *(const bf16x8*)(Kfr + ((cc * 4 + ti) * 2 + dblk) * 512);
                    #pragma unroll
                    for (int half = 0; half < 4; ++half)
                        st[half][ti] = __builtin_amdgcn_mfma_f32_16x16x32_bf16(
                            kf, qf[half][dblk], st[half][ti], 0, 0, 0);
                }

            // ---- p = exp2(s), pack in-register to PV A-fragments ----
            bf16x4 pf[4][4];
            #pragma unroll
            for (int half = 0; half < 4; ++half)
                #pragma unroll
                for (int ti = 0; ti < 4; ++ti) {
                    unsigned u0 = __float_as_uint(EXP2F(st[half][ti][0])) + 0x8000u;
                    unsigned u1 = __float_as_uint(EXP2F(st[half][ti][1])) + 0x8000u;
                    unsigned u2 = __float_as_uint(EXP2F(st[half][ti][2])) + 0x8000u;
                    unsigned u3 = __float_as_uint(EXP2F(st[half][ti][3])) + 0x8000u;
                    union { uint2 u; bf16x4 b; } cv;
                    cv.u.x = __builtin_amdgcn_perm(u1, u0, 0x07060302);
                    cv.u.y = __builtin_amdgcn_perm(u3, u2, 0x07060302);
                    pf[half][ti] = cv.b;
                }

            // ---- V(t) ready (issued at tile top, covered by QK^T+exp2) ----
            if (cc == 0) {
                if (t < 15) { WAITVM(4); } else { WAITVM(0); }
                PHASE_BARRIER();      // Vs visible to all waves
            }

            // ---- PV + ones row-sum via K=16 MFMA, P straight from regs ----
            #pragma unroll
            for (int ti = 0; ti < 4; ++ti) {
                const int s = cc * 4 + ti;
                const unsigned short* vb = VfrB + (s >> 1) * 512 + (s & 1) * 256;
                bf16x4 vf[4];
                #pragma unroll
                for (int nt = 0; nt < 4; ++nt)
                    vf[nt] = *(const bf16x4*)(vb + nt * 2048);
                #pragma unroll
                for (int half = 0; half < 4; ++half) {
                    lacc[half] = __builtin_amdgcn_mfma_f32_16x16x16bf16_1k(
                        pf[half][ti], ones4, lacc[half], 0, 0, 0);
                    #pragma unroll
                    for (int nt = 0; nt < 4; ++nt)
                        oacc[half][nt] = __builtin_amdgcn_mfma_f32_16x16x16bf16_1k(
                            pf[half][ti], vf[nt], oacc[half][nt], 0, 0, 0);
                }
            }
        }

        if (t < 15) {
            WAITVM(0);        // K(t+1): issued a full tile of MFMA ago — free
            PHASE_BARRIER();  // K visible; Vs safe to overwrite next tile
        }
    }

    // ---- normalize + store ----
    #pragma unroll
    for (int half = 0; half < 4; ++half) {
        float il[4];
        #pragma unroll
        for (int r = 0; r < 4; ++r) il[r] = 1.0f / lacc[half][r];
        #pragma unroll
        for (int nt = 0; nt < 4; ++nt) {
            #pragma unroll
            for (int r = 0; r < 4; ++r) {
                size_t orow = (size_t)(b * LQ_ + qt * 256 + w * 64 + half * 16 + quad * 4 + r);
                Out[orow * 1024 + h * 64 + nt * 16 + l15] = oacc[half][nt][r] * il[r];
            }
        }
    }
}

// ---------------------------------------------------------------------------
extern "C" void kernel_launch(void* const* d_in, const int* in_sizes, int n_in,
                              void* d_out, int out_size, void* d_ws, size_t ws_size,
                              hipStream_t stream) {
    const float* zt = (const float*)d_in[0];
    const float* ic = (const float*)d_in[1];
    const float* Wq = (const float*)d_in[2];
    const float* bq = (const float*)d_in[3];
    const float* Wk = (const float*)d_in[4];
    const float* bk = (const float*)d_in[5];
    const float* Wv = (const float*)d_in[6];
    const float* bv = (const float*)d_in[7];
    float* out = (float*)d_out;

    const size_t M8 = (size_t)8192 * 1024;
    const size_t M1 = (size_t)1024 * 1024;
    unsigned short* Qb  = (unsigned short*)d_ws;
    unsigned short* Kb  = Qb  + M8;
    unsigned short* Vb  = Kb  + M8;
    unsigned short* Xz  = Vb  + M8;
    unsigned short* Xi  = Xz  + M8;
    unsigned short* Wqb = Xi  + M8;
    unsigned short* Wkb = Wqb + M1;
    unsigned short* Wvb = Wkb + M1;
    unsigned short* Vtb = Xz;                // Xz dead after qkv_gemm

    const float qscale = 0.125f * 1.44269504088896f;  // 1/sqrt(64) * log2(e)

    dim3 gcv(4096, 5);
    cvt_all<<<gcv, 256, 0, stream>>>(zt, Xz, ic, Xi,
                                     Wq, Wqb, qscale, Wk, Wkb, Wv, Wvb,
                                     (int)M8, (int)M1);

    dim3 gproj(32, 12);                      // m-tile (8192/256), proj*4 + n-tile
    qkv_gemm<<<gproj, 512, 0, stream>>>(Xz, Xi, Wqb, Wkb, Wvb,
                                        bq, bk, bv, qscale, Qb, Kb, Vb);

    dim3 gtr(32, 16, 4);
    transpose_v<<<gtr, 256, 0, stream>>>(Vb, Vtb);

    dim3 gattn(8, 16, 4);                    // flattened+swizzled inside kernel
    attn_kernel<<<gattn, 256, 0, stream>>>(Qb, Kb, Vtb, out);
}

// Round 6
// 290.945 us; speedup vs baseline: 1.0686x; 1.0582x over previous
//
#include <hip/hip_runtime.h>
#include <hip/hip_bf16.h>
#include <cstdint>

#define B_  4
#define LQ_ 2048
#define LK_ 2048
#define D_  1024
#define H_  16
#define HD_ 64

typedef __attribute__((ext_vector_type(8))) short bf16x8;   // 8 bf16 in 4 VGPRs
typedef __attribute__((ext_vector_type(4))) float f32x4;    // MFMA C/D

#if defined(__has_builtin)
#if __has_builtin(__builtin_amdgcn_exp2f)
#define EXP2F(x) __builtin_amdgcn_exp2f(x)
#else
#define EXP2F(x) exp2f(x)
#endif
#else
#define EXP2F(x) exp2f(x)
#endif

__device__ __forceinline__ unsigned short f2b(float f) {   // RNE
    union { float f; unsigned u; } v; v.f = f;
    unsigned u = v.u;
    unsigned r = (u + 0x7fffu + ((u >> 16) & 1u)) >> 16;
    return (unsigned short)r;
}

// async global->LDS, 16B per lane. LDS dest: wave-uniform base + lane*16.
__device__ __forceinline__ void gl_lds16(const unsigned short* g, unsigned short* l) {
    __builtin_amdgcn_global_load_lds(
        (const __attribute__((address_space(1))) unsigned int*)(g),
        (__attribute__((address_space(3))) unsigned int*)(l),
        16, 0, 0);
}

#define PHASE_BARRIER() do { \
    __builtin_amdgcn_sched_barrier(0); \
    __builtin_amdgcn_s_barrier(); \
    __builtin_amdgcn_sched_barrier(0); } while (0)

#define WAITVM(N) do { \
    asm volatile("s_waitcnt vmcnt(" #N ")" ::: "memory"); \
    __builtin_amdgcn_sched_barrier(0); } while (0)

// ---------------------------------------------------------------------------
// Fused fp32->bf16 for all 5 tensors; blockIdx.y selects. Wq scaled by s0.
// ---------------------------------------------------------------------------
__global__ void cvt_all(const float* __restrict__ a0, unsigned short* __restrict__ d0,
                        const float* __restrict__ a1, unsigned short* __restrict__ d1,
                        const float* __restrict__ w0, unsigned short* __restrict__ e0, float s0,
                        const float* __restrict__ w1, unsigned short* __restrict__ e1,
                        const float* __restrict__ w2, unsigned short* __restrict__ e2,
                        int nact, int nw) {
    const float* in; unsigned short* out; float s = 1.0f; int n;
    switch (blockIdx.y) {
        case 0: in = a0; out = d0; n = nact; break;
        case 1: in = a1; out = d1; n = nact; break;
        case 2: in = w0; out = e0; n = nw; s = s0; break;
        case 3: in = w1; out = e1; n = nw; break;
        default: in = w2; out = e2; n = nw; break;
    }
    int i = (blockIdx.x * blockDim.x + threadIdx.x) * 8;
    int stride = gridDim.x * blockDim.x * 8;
    for (; i < n; i += stride) {
        float4 x = *(const float4*)(in + i);
        float4 y = *(const float4*)(in + i + 4);
        bf16x8 v;
        v[0] = (short)f2b(x.x * s); v[1] = (short)f2b(x.y * s);
        v[2] = (short)f2b(x.z * s); v[3] = (short)f2b(x.w * s);
        v[4] = (short)f2b(y.x * s); v[5] = (short)f2b(y.y * s);
        v[6] = (short)f2b(y.z * s); v[7] = (short)f2b(y.w * s);
        *(bf16x8*)(out + i) = v;
    }
}

// ---------------------------------------------------------------------------
// Fused QKV projection GEMM — round-1 schedule (measured best ~91us).
// 256x256 tile, BK=64, 8 waves (2M x 4N), 4-phase counted-vmcnt (T3+T4+T5),
// 4-slot half-tile LDS ring (128KB), fragment-ordered.
// NEW (round 6): the V projection (proj==2) writes its output DIRECTLY in
// transposed layout Vt[(b*1024 + col)*2048 + tok] — acc[i][j][r] has r =
// 4 consecutive tokens for a fixed col, so a packed uint2 (4 bf16 along tok)
// store gives 32B-contiguous segments per quad group: same coalescing
// quality as the row-major epilogue. This deletes the transpose_v kernel
// (64MB HBM round-trip + a launch gap).
// ---------------------------------------------------------------------------
__global__ __launch_bounds__(512, 2) void qkv_gemm(
    const unsigned short* __restrict__ Xq,
    const unsigned short* __restrict__ Xkv,
    const unsigned short* __restrict__ Wqb, const unsigned short* __restrict__ Wkb,
    const unsigned short* __restrict__ Wvb,
    const float* __restrict__ bq, const float* __restrict__ bk,
    const float* __restrict__ bv, float qscale,
    unsigned short* __restrict__ Qb, unsigned short* __restrict__ Kb,
    unsigned short* __restrict__ Vtb)
{
    __shared__ unsigned short AS[4][8192];   // slot (2t+kh)&3 : 16 frags x 512
    __shared__ unsigned short BS[4][8192];

    const int proj = blockIdx.y >> 2;
    const int nt0  = blockIdx.y & 3;
    const unsigned short* X = (proj == 0) ? Xq : Xkv;
    const unsigned short* W = (proj == 0) ? Wqb : (proj == 1 ? Wkb : Wvb);
    const float* bias       = (proj == 0) ? bq  : (proj == 1 ? bk  : bv);
    const float bscale      = (proj == 0) ? qscale : 1.0f;

    const int tid  = threadIdx.x;
    const int lane = tid & 63;
    const int w    = tid >> 6;                 // 0..7
    const int wm   = w & 1, wn = w >> 1;       // 2M x 4N wave grid
    const int m0   = blockIdx.x * 256;
    const int n0   = nt0 * 256;
    const int l15  = lane & 15, quad = lane >> 4;

    f32x4 acc[8][4] = {};

    // staging sources: wave w stages frags w*2, w*2+1 of each 16-frag half
    const unsigned short* gA0 = X + (size_t)(m0 + (w * 2) * 16 + l15) * 1024 + quad * 8;
    const unsigned short* gA1 = gA0 + 16 * 1024;
    const unsigned short* gB0 = W + (size_t)(n0 + (w * 2) * 16 + l15) * 1024 + quad * 8;
    const unsigned short* gB1 = gB0 + 16 * 1024;

#define STAGE_A(slot, koff) do { \
    gl_lds16(gA0 + (koff), &AS[slot][(w * 2) * 512 + lane * 8]); \
    gl_lds16(gA1 + (koff), &AS[slot][(w * 2 + 1) * 512 + lane * 8]); } while (0)
#define STAGE_B(slot, koff) do { \
    gl_lds16(gB0 + (koff), &BS[slot][(w * 2) * 512 + lane * 8]); \
    gl_lds16(gB1 + (koff), &BS[slot][(w * 2 + 1) * 512 + lane * 8]); } while (0)

    const int aoff = (wm * 8) * 512 + lane * 8;   // my 8 m-frags
    const int boff = (wn * 4) * 512 + lane * 8;   // my 4 n-frags

    // prologue: tiles 0 (both halves) + tile 1 kh0, in ring-issue order
    STAGE_A(0, 0);   STAGE_B(0, 0);
    STAGE_A(1, 32);  STAGE_B(1, 32);
    STAGE_A(2, 64);  STAGE_B(2, 64);
    WAITVM(8);
    __builtin_amdgcn_s_barrier();
    __builtin_amdgcn_sched_barrier(0);

    #pragma unroll 2
    for (int t = 0; t < 16; ++t) {
        const int s0 = (2 * t) & 3;
        const int s1 = (2 * t + 1) & 3;
        const int s3 = (2 * t + 3) & 3;

        bf16x8 af[8], bf0, bf1;

        // ---- P1: kh0, n-frags 0,1 ----
        #pragma unroll
        for (int i = 0; i < 8; ++i)
            af[i] = *(const bf16x8*)(&AS[s0][aoff + i * 512]);
        bf0 = *(const bf16x8*)(&BS[s0][boff]);
        bf1 = *(const bf16x8*)(&BS[s0][boff + 512]);
        PHASE_BARRIER();
        __builtin_amdgcn_s_setprio(1);
        #pragma unroll
        for (int i = 0; i < 8; ++i) {
            acc[i][0] = __builtin_amdgcn_mfma_f32_16x16x32_bf16(af[i], bf0, acc[i][0], 0, 0, 0);
            acc[i][1] = __builtin_amdgcn_mfma_f32_16x16x32_bf16(af[i], bf1, acc[i][1], 0, 0, 0);
        }
        __builtin_amdgcn_s_setprio(0);
        if (t < 15) STAGE_A(s3, (t + 1) * 64 + 32);

        // ---- P2: kh0, n-frags 2,3 (af reused) ----
        bf0 = *(const bf16x8*)(&BS[s0][boff + 1024]);
        bf1 = *(const bf16x8*)(&BS[s0][boff + 1536]);
        if (t < 14) { WAITVM(6); } else { WAITVM(0); }
        PHASE_BARRIER();
        __builtin_amdgcn_s_setprio(1);
        #pragma unroll
        for (int i = 0; i < 8; ++i) {
            acc[i][2] = __builtin_amdgcn_mfma_f32_16x16x32_bf16(af[i], bf0, acc[i][2], 0, 0, 0);
            acc[i][3] = __builtin_amdgcn_mfma_f32_16x16x32_bf16(af[i], bf1, acc[i][3], 0, 0, 0);
        }
        __builtin_amdgcn_s_setprio(0);
        if (t < 15) STAGE_B(s3, (t + 1) * 64 + 32);

        // ---- P3: kh1, n-frags 0,1 ----
        #pragma unroll
        for (int i = 0; i < 8; ++i)
            af[i] = *(const bf16x8*)(&AS[s1][aoff + i * 512]);
        bf0 = *(const bf16x8*)(&BS[s1][boff]);
        bf1 = *(const bf16x8*)(&BS[s1][boff + 512]);
        PHASE_BARRIER();
        __builtin_amdgcn_s_setprio(1);
        #pragma unroll
        for (int i = 0; i < 8; ++i) {
            acc[i][0] = __builtin_amdgcn_mfma_f32_16x16x32_bf16(af[i], bf0, acc[i][0], 0, 0, 0);
            acc[i][1] = __builtin_amdgcn_mfma_f32_16x16x32_bf16(af[i], bf1, acc[i][1], 0, 0, 0);
        }
        __builtin_amdgcn_s_setprio(0);
        if (t < 14) STAGE_A(s0, (t + 2) * 64);

        // ---- P4: kh1, n-frags 2,3 ----
        bf0 = *(const bf16x8*)(&BS[s1][boff + 1024]);
        bf1 = *(const bf16x8*)(&BS[s1][boff + 1536]);
        if (t < 14) { WAITVM(6); } else if (t == 14) { WAITVM(4); }
        PHASE_BARRIER();
        __builtin_amdgcn_s_setprio(1);
        #pragma unroll
        for (int i = 0; i < 8; ++i) {
            acc[i][2] = __builtin_amdgcn_mfma_f32_16x16x32_bf16(af[i], bf0, acc[i][2], 0, 0, 0);
            acc[i][3] = __builtin_amdgcn_mfma_f32_16x16x32_bf16(af[i], bf1, acc[i][3], 0, 0, 0);
        }
        __builtin_amdgcn_s_setprio(0);
        if (t < 14) STAGE_B(s0, (t + 2) * 64);
    }

#undef STAGE_A
#undef STAGE_B

    float bvv[4];
    #pragma unroll
    for (int j = 0; j < 4; ++j)
        bvv[j] = bias[n0 + wn * 64 + j * 16 + l15] * bscale;

    if (proj == 2) {
        // ---- transposed epilogue: write Vt[(b*1024+col)*2048 + tok] ----
        #pragma unroll
        for (int i = 0; i < 8; ++i) {
            int row = m0 + wm * 128 + i * 16 + quad * 4;   // token base (r=0..3)
            int bb  = row >> 11;
            int tt  = row & 2047;
            #pragma unroll
            for (int j = 0; j < 4; ++j) {
                int col = n0 + wn * 64 + j * 16 + l15;
                unsigned s0v = f2b(acc[i][j][0] + bvv[j]);
                unsigned s1v = f2b(acc[i][j][1] + bvv[j]);
                unsigned s2v = f2b(acc[i][j][2] + bvv[j]);
                unsigned s3v = f2b(acc[i][j][3] + bvv[j]);
                uint2 pk;
                pk.x = s0v | (s1v << 16);
                pk.y = s2v | (s3v << 16);
                *(uint2*)(Vtb + ((size_t)(bb * 1024 + col)) * 2048 + tt) = pk;
            }
        }
    } else {
        unsigned short* Y = (proj == 0) ? Qb : Kb;
        #pragma unroll
        for (int i = 0; i < 8; ++i) {
            #pragma unroll
            for (int r = 0; r < 4; ++r) {
                int row = m0 + wm * 128 + i * 16 + quad * 4 + r;
                unsigned short* yp = Y + (size_t)row * 1024 + n0 + wn * 64;
                #pragma unroll
                for (int j = 0; j < 4; ++j)
                    yp[j * 16 + l15] = f2b(acc[i][j][r] + bvv[j]);
            }
        }
    }
}

// ---------------------------------------------------------------------------
// Flash attention v8 (round-3 version, measured 96.8us): shared LDS staging
// of K and V + XCD swizzle + K double-buffer with counted waits.
// LDS: K dbuf 32K + Vs 16K + Ps 32K = 80KB -> 2 blocks/CU.
// (v9's K=16 PV reverted: legacy K=16 MFMA costs the same cycles as K=32
// for half the FLOPs -> PV MFMA cost doubled, 96.8 -> 109.4us regression.)
// ---------------------------------------------------------------------------
__global__ __launch_bounds__(256, 2) void attn_kernel(
    const unsigned short* __restrict__ Q,
    const unsigned short* __restrict__ Kp,
    const unsigned short* __restrict__ Vt,
    float* __restrict__ Out)
{
    __shared__ unsigned short Ks[2][16 * 512]; // frag f=kt*2+dblk: K[kt*16+l15][dblk*32+quad*8+j]
    __shared__ unsigned short Vs[16 * 512];    // frag f=nt*4+hb:  V^T[nt*16+l15][hb*32+quad*8+j]
    __shared__ unsigned short Ps[4][4096];     // per-wave, per-half 1024: P[16q][64k] frag-ordered

    const int tid  = threadIdx.x;
    const int lane = tid & 63;
    const int w    = tid >> 6;
    const int l15  = lane & 15, quad = lane >> 4;

    // XCD swizzle: all 8 q-tiles of a (b,h) group share bid%8 -> same XCD,
    // K/V stay L2-resident (proven r2: FETCH 141MB -> 25MB).
    const int bid = blockIdx.x + (blockIdx.y << 3) + (blockIdx.z << 7);
    const int glo = bid & 7;
    const int jx  = bid >> 3;          // 0..63
    const int qt  = jx & 7;
    const int g   = glo + ((jx >> 3) << 3);   // 0..63: (b,h) group
    const int h   = g & 15;
    const int b   = g >> 4;

    bf16x8 qf[4][2];
    #pragma unroll
    for (int half = 0; half < 4; ++half) {
        const unsigned short* qptr =
            Q + (size_t)(b * LQ_ + qt * 256 + w * 64 + half * 16 + l15) * 1024 + h * 64;
        qf[half][0] = *(const bf16x8*)(qptr + quad * 8);
        qf[half][1] = *(const bf16x8*)(qptr + 32 + quad * 8);
    }

    bf16x8 ones;
    #pragma unroll
    for (int j = 0; j < 8; ++j) ones[j] = (short)0x3F80;   // bf16 1.0

    f32x4 oacc[4][4] = {};
    f32x4 lacc[4]    = {};

    const unsigned short* Kbase = Kp + (size_t)b * LK_ * 1024 + h * 64;
    const unsigned short* Vbase = Vt + (size_t)(b * 16 + h) * 64 * 2048;

    const unsigned short* gK[4];
    unsigned short* lK[4];                    // buffer-0 LDS dests
    const unsigned short* gV[4];
    unsigned short* lV[4];
    #pragma unroll
    for (int j = 0; j < 4; ++j) {
        int kt = w + (j >> 1) * 4, dblk = j & 1;
        gK[j] = Kbase + (size_t)(kt * 16 + l15) * 1024 + dblk * 32 + quad * 8;
        lK[j] = &Ks[0][(kt * 2 + dblk) * 512 + lane * 8];
        gV[j] = Vbase + (size_t)(w * 16 + l15) * 2048 + j * 32 + quad * 8;
        lV[j] = &Vs[(w * 4 + j) * 512 + lane * 8];
    }

    // P region: element (q,k) at half*1024 + (k>>3)*128 + q*8 + (k&7)
    const int pws = (quad >> 1) * 128 + l15 * 8 + (quad & 1) * 4;
    unsigned short* PwB = &Ps[w][pws];            // + half*1024 + ti*256
    const unsigned short* PrB = &Ps[w][lane * 8]; // + half*1024 + hbl*512
    const unsigned short* KfrB = &Ks[0][lane * 8];
    const unsigned short* Vfr = &Vs[lane * 8];

    // prologue: stage K(0) into buffer 0
    #pragma unroll
    for (int j = 0; j < 4; ++j) gl_lds16(gK[j], lK[j]);

    for (int t = 0; t < 16; ++t) {
        const int cur = t & 1;
        const int k0 = t * 128;

        // stage V(t); prefetch K(t+1) into other buffer
        #pragma unroll
        for (int j = 0; j < 4; ++j) gl_lds16(gV[j] + k0, lV[j]);
        if (t < 15) {
            const int stoff = (cur ^ 1) * 8192;
            #pragma unroll
            for (int j = 0; j < 4; ++j)
                gl_lds16(gK[j] + (size_t)(t + 1) * (128 * 1024), lK[j] + stoff);
        }
        if (t == 0) {          // K(0) landed (V(0)+K(1) = 8 still in flight)
            WAITVM(8);
            PHASE_BARRIER();
        }
        const unsigned short* Kfr = KfrB + cur * 8192;

        #pragma unroll
        for (int cc = 0; cc < 2; ++cc) {          // two 64-key chunks
            // ---- QK^T, all 4 halves share each kf read ----
            f32x4 st[4][4] = {};
            #pragma unroll
            for (int ti = 0; ti < 4; ++ti)
                #pragma unroll
                for (int dblk = 0; dblk < 2; ++dblk) {
                    bf16x8 kf = *(const bf16x8*)(Kfr + ((cc * 4 + ti) * 2 + dblk) * 512);
                    #pragma unroll
                    for (int half = 0; half < 4; ++half)
                        st[half][ti] = __builtin_amdgcn_mfma_f32_16x16x32_bf16(
                            kf, qf[half][dblk], st[half][ti], 0, 0, 0);
                }

            // ---- p = exp2(s); pack (RHU) into per-half P regions ----
            #pragma unroll
            for (int half = 0; half < 4; ++half) {
                unsigned short* pw = PwB + half * 1024;
                #pragma unroll
                for (int ti = 0; ti < 4; ++ti) {
                    unsigned u0 = __float_as_uint(EXP2F(st[half][ti][0])) + 0x8000u;
                    unsigned u1 = __float_as_uint(EXP2F(st[half][ti][1])) + 0x8000u;
                    unsigned u2 = __float_as_uint(EXP2F(st[half][ti][2])) + 0x8000u;
                    unsigned u3 = __float_as_uint(EXP2F(st[half][ti][3])) + 0x8000u;
                    uint2 pk;
                    pk.x = __builtin_amdgcn_perm(u1, u0, 0x07060302);
                    pk.y = __builtin_amdgcn_perm(u3, u2, 0x07060302);
                    *(uint2*)(pw + ti * 256) = pk;
                }
            }

            // ---- after chunk0's compute has covered V latency: V ready ----
            if (cc == 0) {
                if (t < 15) { WAITVM(4); } else { WAITVM(0); }
                PHASE_BARRIER();      // Vs visible to all waves
            }

            // ---- PV + ones row-sum; vf read once per (nt,hbl), shared ----
            #pragma unroll
            for (int hbl = 0; hbl < 2; ++hbl) {
                bf16x8 pf[4];
                #pragma unroll
                for (int half = 0; half < 4; ++half) {
                    pf[half] = *(const bf16x8*)(PrB + half * 1024 + hbl * 512);
                    lacc[half] = __builtin_amdgcn_mfma_f32_16x16x32_bf16(
                        pf[half], ones, lacc[half], 0, 0, 0);
                }
                int hb = cc * 2 + hbl;
                #pragma unroll
                for (int nt = 0; nt < 4; ++nt) {
                    bf16x8 vf = *(const bf16x8*)(Vfr + (nt * 4 + hb) * 512);
                    #pragma unroll
                    for (int half = 0; half < 4; ++half)
                        oacc[half][nt] = __builtin_amdgcn_mfma_f32_16x16x32_bf16(
                            pf[half], vf, oacc[half][nt], 0, 0, 0);
                }
            }
        }

        if (t < 15) {
            WAITVM(0);        // K(t+1): issued a full tile of MFMA ago — free
            PHASE_BARRIER();  // K visible; Vs safe to overwrite next tile
        }
    }

    // ---- normalize + store ----
    #pragma unroll
    for (int half = 0; half < 4; ++half) {
        float il[4];
        #pragma unroll
        for (int r = 0; r < 4; ++r) il[r] = 1.0f / lacc[half][r];
        #pragma unroll
        for (int nt = 0; nt < 4; ++nt) {
            #pragma unroll
            for (int r = 0; r < 4; ++r) {
                size_t orow = (size_t)(b * LQ_ + qt * 256 + w * 64 + half * 16 + quad * 4 + r);
                Out[orow * 1024 + h * 64 + nt * 16 + l15] = oacc[half][nt][r] * il[r];
            }
        }
    }
}

// ---------------------------------------------------------------------------
extern "C" void kernel_launch(void* const* d_in, const int* in_sizes, int n_in,
                              void* d_out, int out_size, void* d_ws, size_t ws_size,
                              hipStream_t stream) {
    const float* zt = (const float*)d_in[0];
    const float* ic = (const float*)d_in[1];
    const float* Wq = (const float*)d_in[2];
    const float* bq = (const float*)d_in[3];
    const float* Wk = (const float*)d_in[4];
    const float* bk = (const float*)d_in[5];
    const float* Wv = (const float*)d_in[6];
    const float* bv = (const float*)d_in[7];
    float* out = (float*)d_out;

    const size_t M8 = (size_t)8192 * 1024;
    const size_t M1 = (size_t)1024 * 1024;
    unsigned short* Qb  = (unsigned short*)d_ws;
    unsigned short* Kb  = Qb  + M8;
    unsigned short* Vtb = Kb  + M8;          // V written transposed by qkv_gemm
    unsigned short* Xz  = Vtb + M8;
    unsigned short* Xi  = Xz  + M8;
    unsigned short* Wqb = Xi  + M8;
    unsigned short* Wkb = Wqb + M1;
    unsigned short* Wvb = Wkb + M1;

    const float qscale = 0.125f * 1.44269504088896f;  // 1/sqrt(64) * log2(e)

    dim3 gcv(4096, 5);
    cvt_all<<<gcv, 256, 0, stream>>>(zt, Xz, ic, Xi,
                                     Wq, Wqb, qscale, Wk, Wkb, Wv, Wvb,
                                     (int)M8, (int)M1);

    dim3 gproj(32, 12);                      // m-tile (8192/256), proj*4 + n-tile
    qkv_gemm<<<gproj, 512, 0, stream>>>(Xz, Xi, Wqb, Wkb, Wvb,
                                        bq, bk, bv, qscale, Qb, Kb, Vtb);

    dim3 gattn(8, 16, 4);                    // flattened+swizzled inside kernel
    attn_kernel<<<gattn, 256, 0, stream>>>(Qb, Kb, Vtb, out);
}